// Round 12
// baseline (4898.493 us; speedup 1.0000x reference)
//
#include <hip/hip_runtime.h>
#include <hip/hip_bf16.h>

#define NROW 1024

typedef float f4v __attribute__((ext_vector_type(4)));

__device__ __forceinline__ float wave_reduce(float v) {
    for (int off = 32; off; off >>= 1) v += __shfl_down(v, off);
    return v;
}

// Stage 1: h[i,:] = in[i,:] @ W ; e1[i] = h[i,:] . a[:F].
// 4 rows/block, 1024 threads. grid = 256. REPS: measurement repetition (pure fn).
template <int K, int F>
__global__ void __launch_bounds__(1024) gemm_e1_kernel(const float* __restrict__ in,
                                                       const float* __restrict__ W,
                                                       const float* __restrict__ a,
                                                       float* __restrict__ h,
                                                       float* __restrict__ e1,
                                                       int reps) {
    __shared__ float srow[4 * K];
    __shared__ float pacc[1024];
    __shared__ float redf[8];
    int t = threadIdx.x;
    int i0 = blockIdx.x * 4;
    for (int rep = 0; rep < reps; ++rep) {
        for (int idx = t; idx < 4 * K; idx += 1024) srow[idx] = in[i0 * K + idx];
        __syncthreads();
        {
            int c = t & (F - 1);
            int rh = t / F;               // 0..7
            int r = rh & 3, half = rh >> 2;
            const float* sp = srow + r * K + half * (K / 2);
            const float* wp = W + (size_t)(half * (K / 2)) * F + c;
            float a0 = 0.f, a1 = 0.f;
#pragma unroll 4
            for (int k = 0; k < K / 2; k += 2) {
                a0 = fmaf(sp[k], wp[(size_t)k * F], a0);
                a1 = fmaf(sp[k + 1], wp[(size_t)(k + 1) * F], a1);
            }
            pacc[t] = a0 + a1;
        }
        __syncthreads();
        if (t < 4 * F) {
            float accf = pacc[t] + pacc[t + 4 * F];
            int c = t & (F - 1), r = t / F;
            h[(i0 + r) * F + c] = accf;
            float p = wave_reduce(accf * a[c]);
            if ((t & 63) == 0) redf[t >> 6] = p;
        }
        __syncthreads();
        constexpr int WPR = F / 64;
        if (t < 4) {
            float s = 0.f;
#pragma unroll
            for (int w = 0; w < WPR; ++w) s += redf[t * WPR + w];
            e1[i0 + t] = s;
        }
        __syncthreads();
    }
}

// Attention core (round-9 scalar version): 4 rows/block, 1024 threads, grid 256.
template <int F, int G>
__device__ __forceinline__ void attn_core(const float* __restrict__ h,
                                          const int* __restrict__ adj,
                                          const float* __restrict__ e1in,
                                          const float* __restrict__ aprev,
                                          const float* __restrict__ bprev, int i0,
                                          float* wexp_sh, float* E2row, float* cred,
                                          float* redf, float* sinv,
                                          f4v* alpha4, float* orow) {
    constexpr int NQ = 1024 / F;
    int t = threadIdx.x;
    int ib = i0 / F;
    {
        int g = t / F, c = t % F;
        float acc = 0.f;
#pragma unroll 4
        for (int p = g; p < F; p += NQ) acc = fmaf(aprev[F + p], h[(p * G + ib) * F + c], acc);
        cred[t] = acc;
    }
    __syncthreads();
    if (t < F) {
        float s = 0.f;
#pragma unroll
        for (int g = 0; g < NQ; ++g) s += cred[g * F + t];
        E2row[t] = s;
    }
    __syncthreads();
    {
        float v = e1in[t] + E2row[t & (F - 1)];
        v = v > 0.f ? v : 0.2f * v;
        wexp_sh[t] = expf(v);
    }
    __syncthreads();
    int lane = t & 63, wv = t >> 6;   // 16 waves
    {
        int r = wv & 3;
        const int* arow = adj + (size_t)(i0 + r) * NROW;
        float s = 0.f;
        float* al = (float*)alpha4;
        for (int jb = (wv >> 2); jb < 16; jb += 4) {
            int j = jb * 64 + lane;
            float av = (arow[j] > 0) ? wexp_sh[j] : 0.f;
            al[j * 4 + r] = av;
            s += av;
        }
        s = wave_reduce(s);
        if (lane == 0) redf[wv] = s;
    }
    __syncthreads();
    if (t < 4) sinv[t] = 1.f / (redf[t] + redf[t + 4] + redf[t + 8] + redf[t + 12]);
    __syncthreads();
    int c = t % F, q = t / F;
    float acc0 = 0.f, acc1 = 0.f, acc2 = 0.f, acc3 = 0.f;
#pragma unroll 8
    for (int j = q; j < NROW; j += NQ) {
        f4v al = alpha4[j];          // wave-uniform j -> LDS broadcast
        float hv = h[j * F + c];
        acc0 = fmaf(al.x, hv, acc0);
        acc1 = fmaf(al.y, hv, acc1);
        acc2 = fmaf(al.z, hv, acc2);
        acc3 = fmaf(al.w, hv, acc3);
    }
    float* cr = cred + t * 4;
    cr[0] = acc0; cr[1] = acc1; cr[2] = acc2; cr[3] = acc3;
    __syncthreads();
    if (t < 4 * F) {
        int rr = t / F, cc = t % F;
        float tot = 0.f;
#pragma unroll
        for (int qq = 0; qq < NQ; ++qq) tot += cred[(qq * F + cc) * 4 + rr];
        float v = tot * sinv[rr];
        v = v > 0.f ? v : 0.f;
        v += bprev[cc];
        v = v > 0.f ? v : 0.f;
        orow[rr * F + cc] = v;
    }
    __syncthreads();
}

// Stages 2,3: attn + next-layer gemm (row-local). FN must be 64. grid 256. REPS.
template <int F, int G, int FN>
__global__ void __launch_bounds__(1024) attn_gemm_kernel(
    const float* __restrict__ h, const int* __restrict__ adj,
    const float* __restrict__ e1in, const float* __restrict__ aprev,
    const float* __restrict__ bprev, const float* __restrict__ Wn,
    const float* __restrict__ an, float* __restrict__ hout,
    float* __restrict__ e1out, int reps) {
    __shared__ float wexp_sh[1024];
    __shared__ float E2row[F];
    __shared__ float cred[4096];
    __shared__ float redf[16];
    __shared__ float sinv[4];
    __shared__ float orow[4 * F];
    __shared__ f4v alpha4[1024];
    int i0 = blockIdx.x * 4;
    int t = threadIdx.x;
    for (int rep = 0; rep < reps; ++rep) {
        attn_core<F, G>(h, adj, e1in, aprev, bprev, i0, wexp_sh, E2row, cred, redf, sinv, alpha4, orow);
        if (t < 4 * FN) {
            int r = t / FN, c = t % FN;
            float acc = 0.f;
#pragma unroll 8
            for (int k = 0; k < F; ++k) acc = fmaf(orow[r * F + k], Wn[k * FN + c], acc);
            hout[(i0 + r) * FN + c] = acc;
            float p = wave_reduce(acc * an[c]);  // FN==64 -> wave index == r
            if ((t & 63) == 0) redf[r] = p;
        }
        __syncthreads();
        if (t < 4) e1out[i0 + t] = redf[t];
        __syncthreads();
    }
}

// Stage 4: attn layer 3 -> xf. grid 256. REPS.
template <int F, int G>
__global__ void __launch_bounds__(1024) attn_xf_kernel(
    const float* __restrict__ h, const int* __restrict__ adj,
    const float* __restrict__ e1in, const float* __restrict__ aprev,
    const float* __restrict__ bprev, float* __restrict__ xf, int reps) {
    __shared__ float wexp_sh[1024];
    __shared__ float E2row[F];
    __shared__ float cred[4096];
    __shared__ float redf[16];
    __shared__ float sinv[4];
    __shared__ float orow[4 * F];
    __shared__ f4v alpha4[1024];
    int i0 = blockIdx.x * 4;
    int t = threadIdx.x;
    for (int rep = 0; rep < reps; ++rep) {
        attn_core<F, G>(h, adj, e1in, aprev, bprev, i0, wexp_sh, E2row, cred, redf, sinv, alpha4, orow);
        if (t < 4 * F) xf[(size_t)i0 * F + t] = orow[t];
        __syncthreads();
    }
}

// Stage 5: head layer 1 (single pass, measured at ~57us). 2 rows/block, 768x512.
__global__ void __launch_bounds__(512) head1_kernel(const float* __restrict__ l1w,
                                                    const float* __restrict__ l1b,
                                                    const float* __restrict__ xf,
                                                    float* __restrict__ t1g) {
    __shared__ float red[16];
    int t = threadIdx.x;
    int r0 = blockIdx.x * 2;
    const f4v* xv = (const f4v*)xf;
    const f4v* w0p = (const f4v*)l1w + (size_t)r0 * 16384;
    const f4v* w1p = w0p + 16384;
    float a0a = 0.f, a0b = 0.f, a1a = 0.f, a1b = 0.f;
#pragma unroll 4
    for (int it = t; it < 16384; it += 512) {
        f4v xx = xv[it];
        f4v w0 = __builtin_nontemporal_load(&w0p[it]);
        f4v w1 = __builtin_nontemporal_load(&w1p[it]);
        a0a = fmaf(w0.x, xx.x, fmaf(w0.y, xx.y, a0a));
        a0b = fmaf(w0.z, xx.z, fmaf(w0.w, xx.w, a0b));
        a1a = fmaf(w1.x, xx.x, fmaf(w1.y, xx.y, a1a));
        a1b = fmaf(w1.z, xx.z, fmaf(w1.w, xx.w, a1b));
    }
    float acc0 = wave_reduce(a0a + a0b);
    float acc1 = wave_reduce(a1a + a1b);
    int lane = t & 63, wv = t >> 6;
    if (lane == 0) { red[wv * 2] = acc0; red[wv * 2 + 1] = acc1; }
    __syncthreads();
    if (t < 2) {
        int row = r0 + t;
        float s = l1b[row];
#pragma unroll
        for (int w = 0; w < 8; ++w) s += red[w * 2 + t];
        t1g[row] = s > 0.f ? s : 0.f;
    }
}

// Stage 6: head layers 2 (sigmoid) + 3. 6 blocks x 256 threads.
__global__ void __launch_bounds__(256) head23_kernel(
    const float* __restrict__ t1g, const float* __restrict__ l2w,
    const float* __restrict__ l2b, const float* __restrict__ l3w,
    const float* __restrict__ l3b, float* __restrict__ out) {
    __shared__ float t1s[256];
    __shared__ float t2s[128];
    int hh = blockIdx.x, t = threadIdx.x, lane = t & 63, wv = t >> 6;
    t1s[t] = t1g[hh * 256 + t];
    __syncthreads();
    float4 tv = ((const float4*)t1s)[lane];
    for (int o = wv; o < 128; o += 4) {
        float4 w4 = ((const float4*)(l2w + ((size_t)hh * 128 + o) * 256))[lane];
        float p = fmaf(w4.x, tv.x, fmaf(w4.y, tv.y, fmaf(w4.z, tv.z, w4.w * tv.w)));
        p = wave_reduce(p);
        if (lane == 0) t2s[o] = 1.f / (1.f + expf(-(p + l2b[hh * 128 + o])));
    }
    __syncthreads();
    if (wv == 0) {
        float p = l3w[hh * 128 + lane] * t2s[lane] +
                  l3w[hh * 128 + 64 + lane] * t2s[64 + lane];
        p = wave_reduce(p);
        if (lane == 0) out[hh] = p + l3b[hh];
    }
}

extern "C" void kernel_launch(void* const* d_in, const int* in_sizes, int n_in,
                              void* d_out, int out_size, void* d_ws, size_t ws_size,
                              hipStream_t stream) {
    const float* x   = (const float*)d_in[0];
    const int*   adj = (const int*)d_in[1];
    const float* W1  = (const float*)d_in[2];
    const float* a1  = (const float*)d_in[3];
    const float* b1  = (const float*)d_in[4];
    const float* W2  = (const float*)d_in[5];
    const float* a2  = (const float*)d_in[6];
    const float* b2  = (const float*)d_in[7];
    const float* W3  = (const float*)d_in[8];
    const float* a3  = (const float*)d_in[9];
    const float* b3  = (const float*)d_in[10];
    const float* l1w = (const float*)d_in[11];
    const float* l1b = (const float*)d_in[12];
    const float* l2w = (const float*)d_in[13];
    const float* l2b = (const float*)d_in[14];
    const float* l3w = (const float*)d_in[15];
    const float* l3b = (const float*)d_in[16];
    float* out = (float*)d_out;

    float* ws = (float*)d_ws;
    float* h1   = ws;            // 1024*128
    float* h2   = ws + 131072;   // 1024*64
    float* h3   = ws + 196608;   // 1024*64
    float* xf   = ws + 262144;   // 1024*64
    float* e1a  = ws + 327680;   // 1024
    float* e1b  = ws + 328704;   // 1024
    float* e1c  = ws + 329728;   // 1024
    float* t1g  = ws + 330752;   // 1536

    // MEASUREMENT ROUND: rep counts push each GAT dispatch above the ~245us
    // harness fills so rocprof top-5 exposes per-stage counters. Pure
    // functions -> repetition is exact (same output every rep).
    gemm_e1_kernel<512, 128><<<256, 1024, 0, stream>>>(x, W1, a1, h1, e1a, 256);
    attn_gemm_kernel<128, 8, 64><<<256, 1024, 0, stream>>>(h1, adj, e1a, a1, b1, W2, a2, h2, e1b, 64);
    attn_gemm_kernel<64, 16, 64><<<256, 1024, 0, stream>>>(h2, adj, e1b, a2, b2, W3, a3, h3, e1c, 128);
    attn_xf_kernel<64, 16><<<256, 1024, 0, stream>>>(h3, adj, e1c, a3, b3, xf, 128);
    head1_kernel<<<768, 512, 0, stream>>>(l1w, l1b, xf, t1g);
    head23_kernel<<<6, 256, 0, stream>>>(t1g, l2w, l2b, l3w, l3b, out);
}

// Round 13
// 125.494 us; speedup vs baseline: 39.0338x; 39.0338x over previous
//
#include <hip/hip_runtime.h>
#include <hip/hip_bf16.h>

#define NROW 1024

typedef float f4v __attribute__((ext_vector_type(4)));

__device__ __forceinline__ float wave_reduce(float v) {
    for (int off = 32; off; off >>= 1) v += __shfl_down(v, off);
    return v;
}

// Stage 1 v2: h[i,:] = in[i,:] @ W ; e1[i] = h[i,:] . a[:F].
// 4 rows/block, 1024 threads = 32 k-splits x 32 col4-groups. grid = 256.
// W loads are float4 (16 independent per thread); x rows transposed in LDS
// and read as b128 broadcast.
template <int K, int F>
__global__ void __launch_bounds__(1024) gemm_e1_kernel(const float* __restrict__ in,
                                                       const float* __restrict__ W,
                                                       const float* __restrict__ a,
                                                       float* __restrict__ h,
                                                       float* __restrict__ e1) {
    constexpr int C4 = F / 4;        // 32 col groups
    constexpr int KS = 1024 / C4;    // 32 k splits
    constexpr int KPT = K / KS;      // 16 k per thread
    __shared__ float srow_t[K * 4];                    // [k][r], 8 KB
    __shared__ __align__(16) float pacc[(KS / 2) * C4 * 4 * 4];  // [r][w][c4] f4v, 32 KB
    __shared__ float redf[4];
    f4v* pacc4 = (f4v*)pacc;
    int t = threadIdx.x;
    int i0 = blockIdx.x * 4;
    for (int idx = t; idx < 4 * K; idx += 1024) {
        int r = idx / K, k = idx % K;
        srow_t[k * 4 + r] = in[i0 * K + idx];
    }
    __syncthreads();
    int c4 = t & (C4 - 1), ks = t >> 5;
    const f4v* W4 = (const f4v*)W;
    const f4v* s4 = (const f4v*)srow_t;
    f4v acc0 = {0.f, 0.f, 0.f, 0.f}, acc1 = acc0, acc2 = acc0, acc3 = acc0;
#pragma unroll
    for (int kk = 0; kk < KPT; ++kk) {
        int k = ks * KPT + kk;
        f4v w = W4[k * C4 + c4];
        f4v s = s4[k];
        acc0 += s.x * w;
        acc1 += s.y * w;
        acc2 += s.z * w;
        acc3 += s.w * w;
    }
    // combine ks-pairs across wave halves (lane ^ 32): wave holds ks=2w,2w+1
#pragma unroll
    for (int comp = 0; comp < 4; ++comp) {
        acc0[comp] += __shfl_xor(acc0[comp], 32);
        acc1[comp] += __shfl_xor(acc1[comp], 32);
        acc2[comp] += __shfl_xor(acc2[comp], 32);
        acc3[comp] += __shfl_xor(acc3[comp], 32);
    }
    if ((t & 32) == 0) {
        int w = ks >> 1;   // 0..15
        pacc4[(0 * (KS / 2) + w) * C4 + c4] = acc0;
        pacc4[(1 * (KS / 2) + w) * C4 + c4] = acc1;
        pacc4[(2 * (KS / 2) + w) * C4 + c4] = acc2;
        pacc4[(3 * (KS / 2) + w) * C4 + c4] = acc3;
    }
    __syncthreads();
    if (t < 4 * C4) {
        int r = t >> 5, cc4 = t & (C4 - 1);
        f4v tot = {0.f, 0.f, 0.f, 0.f};
#pragma unroll
        for (int w = 0; w < KS / 2; ++w) tot += pacc4[(r * (KS / 2) + w) * C4 + cc4];
        ((f4v*)h)[(size_t)(i0 + r) * C4 + cc4] = tot;
        const f4v a4 = ((const f4v*)a)[cc4];
        float p = tot.x * a4.x + tot.y * a4.y + tot.z * a4.z + tot.w * a4.w;
        for (int off = 16; off; off >>= 1) p += __shfl_down(p, off, 32);
        if (cc4 == 0) redf[r] = p;
    }
    __syncthreads();
    if (t < 4) e1[i0 + t] = redf[t];
}

// Attention core (round-9 scalar version): 4 rows/block, 1024 threads, grid 256.
template <int F, int G>
__device__ __forceinline__ void attn_core(const float* __restrict__ h,
                                          const int* __restrict__ adj,
                                          const float* __restrict__ e1in,
                                          const float* __restrict__ aprev,
                                          const float* __restrict__ bprev, int i0,
                                          float* wexp_sh, float* E2row, float* cred,
                                          float* redf, float* sinv,
                                          f4v* alpha4, float* orow) {
    constexpr int NQ = 1024 / F;
    int t = threadIdx.x;
    int ib = i0 / F;
    {
        int g = t / F, c = t % F;
        float acc = 0.f;
#pragma unroll 4
        for (int p = g; p < F; p += NQ) acc = fmaf(aprev[F + p], h[(p * G + ib) * F + c], acc);
        cred[t] = acc;
    }
    __syncthreads();
    if (t < F) {
        float s = 0.f;
#pragma unroll
        for (int g = 0; g < NQ; ++g) s += cred[g * F + t];
        E2row[t] = s;
    }
    __syncthreads();
    {
        float v = e1in[t] + E2row[t & (F - 1)];
        v = v > 0.f ? v : 0.2f * v;
        wexp_sh[t] = expf(v);
    }
    __syncthreads();
    int lane = t & 63, wv = t >> 6;   // 16 waves
    {
        int r = wv & 3;
        const int* arow = adj + (size_t)(i0 + r) * NROW;
        float s = 0.f;
        float* al = (float*)alpha4;
        for (int jb = (wv >> 2); jb < 16; jb += 4) {
            int j = jb * 64 + lane;
            float av = (arow[j] > 0) ? wexp_sh[j] : 0.f;
            al[j * 4 + r] = av;
            s += av;
        }
        s = wave_reduce(s);
        if (lane == 0) redf[wv] = s;
    }
    __syncthreads();
    if (t < 4) sinv[t] = 1.f / (redf[t] + redf[t + 4] + redf[t + 8] + redf[t + 12]);
    __syncthreads();
    int c = t % F, q = t / F;
    float acc0 = 0.f, acc1 = 0.f, acc2 = 0.f, acc3 = 0.f;
#pragma unroll 8
    for (int j = q; j < NROW; j += NQ) {
        f4v al = alpha4[j];          // wave-uniform j -> LDS broadcast
        float hv = h[j * F + c];
        acc0 = fmaf(al.x, hv, acc0);
        acc1 = fmaf(al.y, hv, acc1);
        acc2 = fmaf(al.z, hv, acc2);
        acc3 = fmaf(al.w, hv, acc3);
    }
    float* cr = cred + t * 4;
    cr[0] = acc0; cr[1] = acc1; cr[2] = acc2; cr[3] = acc3;
    __syncthreads();
    if (t < 4 * F) {
        int rr = t / F, cc = t % F;
        float tot = 0.f;
#pragma unroll
        for (int qq = 0; qq < NQ; ++qq) tot += cred[(qq * F + cc) * 4 + rr];
        float v = tot * sinv[rr];
        v = v > 0.f ? v : 0.f;
        v += bprev[cc];
        v = v > 0.f ? v : 0.f;
        orow[rr * F + cc] = v;
    }
    __syncthreads();
}

// Stages 2,3: attn + next-layer gemm (row-local). FN must be 64. grid 256.
template <int F, int G, int FN>
__global__ void __launch_bounds__(1024) attn_gemm_kernel(
    const float* __restrict__ h, const int* __restrict__ adj,
    const float* __restrict__ e1in, const float* __restrict__ aprev,
    const float* __restrict__ bprev, const float* __restrict__ Wn,
    const float* __restrict__ an, float* __restrict__ hout,
    float* __restrict__ e1out) {
    __shared__ float wexp_sh[1024];
    __shared__ float E2row[F];
    __shared__ float cred[4096];
    __shared__ float redf[16];
    __shared__ float sinv[4];
    __shared__ float orow[4 * F];
    __shared__ f4v alpha4[1024];
    int i0 = blockIdx.x * 4;
    attn_core<F, G>(h, adj, e1in, aprev, bprev, i0, wexp_sh, E2row, cred, redf, sinv, alpha4, orow);
    int t = threadIdx.x;
    if (t < 4 * FN) {
        int r = t / FN, c = t % FN;
        float acc = 0.f;
#pragma unroll 8
        for (int k = 0; k < F; ++k) acc = fmaf(orow[r * F + k], Wn[k * FN + c], acc);
        hout[(i0 + r) * FN + c] = acc;
        float p = wave_reduce(acc * an[c]);  // FN==64 -> wave index == r
        if ((t & 63) == 0) redf[r] = p;
    }
    __syncthreads();
    if (t < 4) e1out[i0 + t] = redf[t];
}

// Stage 4: attn layer 3 -> xf. grid 256.
template <int F, int G>
__global__ void __launch_bounds__(1024) attn_xf_kernel(
    const float* __restrict__ h, const int* __restrict__ adj,
    const float* __restrict__ e1in, const float* __restrict__ aprev,
    const float* __restrict__ bprev, float* __restrict__ xf) {
    __shared__ float wexp_sh[1024];
    __shared__ float E2row[F];
    __shared__ float cred[4096];
    __shared__ float redf[16];
    __shared__ float sinv[4];
    __shared__ float orow[4 * F];
    __shared__ f4v alpha4[1024];
    int i0 = blockIdx.x * 4;
    attn_core<F, G>(h, adj, e1in, aprev, bprev, i0, wexp_sh, E2row, cred, redf, sinv, alpha4, orow);
    int t = threadIdx.x;
    if (t < 4 * F) xf[(size_t)i0 * F + t] = orow[t];
}

// Stage 5: head layer 1 (measured ~57us, combined L3+HBM roofline).
// 2 rows/block, 768 blocks x 512 threads, NT loads on l1w.
__global__ void __launch_bounds__(512) head1_kernel(const float* __restrict__ l1w,
                                                    const float* __restrict__ l1b,
                                                    const float* __restrict__ xf,
                                                    float* __restrict__ t1g) {
    __shared__ float red[16];
    int t = threadIdx.x;
    int r0 = blockIdx.x * 2;
    const f4v* xv = (const f4v*)xf;
    const f4v* w0p = (const f4v*)l1w + (size_t)r0 * 16384;
    const f4v* w1p = w0p + 16384;
    float a0a = 0.f, a0b = 0.f, a1a = 0.f, a1b = 0.f;
#pragma unroll 4
    for (int it = t; it < 16384; it += 512) {
        f4v xx = xv[it];
        f4v w0 = __builtin_nontemporal_load(&w0p[it]);
        f4v w1 = __builtin_nontemporal_load(&w1p[it]);
        a0a = fmaf(w0.x, xx.x, fmaf(w0.y, xx.y, a0a));
        a0b = fmaf(w0.z, xx.z, fmaf(w0.w, xx.w, a0b));
        a1a = fmaf(w1.x, xx.x, fmaf(w1.y, xx.y, a1a));
        a1b = fmaf(w1.z, xx.z, fmaf(w1.w, xx.w, a1b));
    }
    float acc0 = wave_reduce(a0a + a0b);
    float acc1 = wave_reduce(a1a + a1b);
    int lane = t & 63, wv = t >> 6;
    if (lane == 0) { red[wv * 2] = acc0; red[wv * 2 + 1] = acc1; }
    __syncthreads();
    if (t < 2) {
        int row = r0 + t;
        float s = l1b[row];
#pragma unroll
        for (int w = 0; w < 8; ++w) s += red[w * 2 + t];
        t1g[row] = s > 0.f ? s : 0.f;
    }
}

// Stage 6: head layers 2 (sigmoid) + 3. 6 blocks x 256 threads.
__global__ void __launch_bounds__(256) head23_kernel(
    const float* __restrict__ t1g, const float* __restrict__ l2w,
    const float* __restrict__ l2b, const float* __restrict__ l3w,
    const float* __restrict__ l3b, float* __restrict__ out) {
    __shared__ float t1s[256];
    __shared__ float t2s[128];
    int hh = blockIdx.x, t = threadIdx.x, lane = t & 63, wv = t >> 6;
    t1s[t] = t1g[hh * 256 + t];
    __syncthreads();
    float4 tv = ((const float4*)t1s)[lane];
    for (int o = wv; o < 128; o += 4) {
        float4 w4 = ((const float4*)(l2w + ((size_t)hh * 128 + o) * 256))[lane];
        float p = fmaf(w4.x, tv.x, fmaf(w4.y, tv.y, fmaf(w4.z, tv.z, w4.w * tv.w)));
        p = wave_reduce(p);
        if (lane == 0) t2s[o] = 1.f / (1.f + expf(-(p + l2b[hh * 128 + o])));
    }
    __syncthreads();
    if (wv == 0) {
        float p = l3w[hh * 128 + lane] * t2s[lane] +
                  l3w[hh * 128 + 64 + lane] * t2s[64 + lane];
        p = wave_reduce(p);
        if (lane == 0) out[hh] = p + l3b[hh];
    }
}

extern "C" void kernel_launch(void* const* d_in, const int* in_sizes, int n_in,
                              void* d_out, int out_size, void* d_ws, size_t ws_size,
                              hipStream_t stream) {
    const float* x   = (const float*)d_in[0];
    const int*   adj = (const int*)d_in[1];
    const float* W1  = (const float*)d_in[2];
    const float* a1  = (const float*)d_in[3];
    const float* b1  = (const float*)d_in[4];
    const float* W2  = (const float*)d_in[5];
    const float* a2  = (const float*)d_in[6];
    const float* b2  = (const float*)d_in[7];
    const float* W3  = (const float*)d_in[8];
    const float* a3  = (const float*)d_in[9];
    const float* b3  = (const float*)d_in[10];
    const float* l1w = (const float*)d_in[11];
    const float* l1b = (const float*)d_in[12];
    const float* l2w = (const float*)d_in[13];
    const float* l2b = (const float*)d_in[14];
    const float* l3w = (const float*)d_in[15];
    const float* l3b = (const float*)d_in[16];
    float* out = (float*)d_out;

    float* ws = (float*)d_ws;
    float* h1   = ws;            // 1024*128
    float* h2   = ws + 131072;   // 1024*64
    float* h3   = ws + 196608;   // 1024*64
    float* xf   = ws + 262144;   // 1024*64
    float* e1a  = ws + 327680;   // 1024
    float* e1b  = ws + 328704;   // 1024
    float* e1c  = ws + 329728;   // 1024
    float* t1g  = ws + 330752;   // 1536

    gemm_e1_kernel<512, 128><<<256, 1024, 0, stream>>>(x, W1, a1, h1, e1a);
    attn_gemm_kernel<128, 8, 64><<<256, 1024, 0, stream>>>(h1, adj, e1a, a1, b1, W2, a2, h2, e1b);
    attn_gemm_kernel<64, 16, 64><<<256, 1024, 0, stream>>>(h2, adj, e1b, a2, b2, W3, a3, h3, e1c);
    attn_xf_kernel<64, 16><<<256, 1024, 0, stream>>>(h3, adj, e1c, a3, b3, xf);
    head1_kernel<<<768, 512, 0, stream>>>(l1w, l1b, xf, t1g);
    head23_kernel<<<6, 256, 0, stream>>>(t1g, l2w, l2b, l3w, l3b, out);
}